// Round 1
// baseline (582.209 us; speedup 1.0000x reference)
//
#include <hip/hip_runtime.h>
#include <hip/hip_bf16.h>
#include <cstdint>
#include <cstddef>

#define H_     8
#define KV_    4
#define D_     256
#define HID_   2560
#define S_     32
#define L_     8192
#define NQ_    64          // G*S query rows per kv head
#define LKEEP_ (L_ - S_)   // 8160

// ---------------- Kernel A: fused QKV projection, K-split x4 ----------------
// out: [4 ksplit][32][4096] partial sums. cols 0..2047=Wq, 2048..3071=Wk, 3072..4095=Wv
__global__ __launch_bounds__(256) void k_qkv_proj(
    const float* __restrict__ hidden,
    const float* __restrict__ Wq, const float* __restrict__ Wk, const float* __restrict__ Wv,
    float* __restrict__ outp)
{
    const int col0 = blockIdx.x * 64;       // 0..4032
    const int kp   = blockIdx.y;            // 0..3
    const float* W; int ldw, wb;
    if (col0 < 2048)      { W = Wq; ldw = 2048; wb = col0; }
    else if (col0 < 3072) { W = Wk; ldw = 1024; wb = col0 - 2048; }
    else                  { W = Wv; ldw = 1024; wb = col0 - 3072; }
    const int kbase = kp * 640;
    const int tc = (threadIdx.x & 31) * 2;  // 2 cols per thread
    const int tr = threadIdx.x >> 5;        // row group 0..7 (rows tr, tr+8, tr+16, tr+24)
    __shared__ float hs[32][68];
    float acc[4][2] = {};
    for (int e0 = 0; e0 < 640; e0 += 64) {
        #pragma unroll
        for (int i = 0; i < 8; i++) {
            int idx = i * 256 + threadIdx.x;
            hs[idx >> 6][idx & 63] = hidden[(idx >> 6) * HID_ + kbase + e0 + (idx & 63)];
        }
        __syncthreads();
        #pragma unroll 4
        for (int e = 0; e < 64; e += 4) {
            float4 h0 = *(const float4*)&hs[tr][e];
            float4 h1 = *(const float4*)&hs[tr + 8][e];
            float4 h2 = *(const float4*)&hs[tr + 16][e];
            float4 h3 = *(const float4*)&hs[tr + 24][e];
            #pragma unroll
            for (int j = 0; j < 4; j++) {
                float2 w = *(const float2*)&W[(size_t)(kbase + e0 + e + j) * ldw + wb + tc];
                float a0 = ((const float*)&h0)[j];
                float a1 = ((const float*)&h1)[j];
                float a2 = ((const float*)&h2)[j];
                float a3 = ((const float*)&h3)[j];
                acc[0][0] = fmaf(a0, w.x, acc[0][0]); acc[0][1] = fmaf(a0, w.y, acc[0][1]);
                acc[1][0] = fmaf(a1, w.x, acc[1][0]); acc[1][1] = fmaf(a1, w.y, acc[1][1]);
                acc[2][0] = fmaf(a2, w.x, acc[2][0]); acc[2][1] = fmaf(a2, w.y, acc[2][1]);
                acc[3][0] = fmaf(a3, w.x, acc[3][0]); acc[3][1] = fmaf(a3, w.y, acc[3][1]);
            }
        }
        __syncthreads();
    }
    float* op = outp + (size_t)kp * (32 * 4096);
    #pragma unroll
    for (int i = 0; i < 4; i++) {
        int r = tr + i * 8;
        *(float2*)&op[r * 4096 + col0 + tc] = make_float2(acc[i][0], acc[i][1]);
    }
}

// ---------------- Kernel B: sum ksplit partials + RMSNorm + RoPE ----------------
// grid 512 = 16 type-heads (8 q, 4 k, 4 v) x 32 seq
__global__ __launch_bounds__(256) void k_rms_rope(
    const float* __restrict__ qkv_part,
    const float* __restrict__ cosb, const float* __restrict__ sinb,
    const float* __restrict__ qw, const float* __restrict__ kw, const float* __restrict__ vw,
    float* __restrict__ q, float* __restrict__ kn, float* __restrict__ vn)
{
    const int b = blockIdx.x;
    const int th = b >> 5;     // 0..15
    const int s  = b & 31;
    const int d  = threadIdx.x;
    const float* w; float* op; int col; bool rope;
    if (th < 8)       { w = qw; col = th * 256;              op = q  + ((size_t)(th * 32 + s)) * 256;        rope = true;  }
    else if (th < 12) { w = kw; col = 2048 + (th - 8) * 256; op = kn + ((size_t)((th - 8) * 32 + s)) * 256;  rope = true;  }
    else              { w = vw; col = 3072 + (th - 12) * 256;op = vn + ((size_t)((th - 12) * 32 + s)) * 256; rope = false; }
    const int base = s * 4096 + col + d;
    float x = qkv_part[base] + qkv_part[131072 + base] + qkv_part[262144 + base] + qkv_part[393216 + base];
    float ss = x * x;
    #pragma unroll
    for (int m = 32; m; m >>= 1) ss += __shfl_xor(ss, m, 64);
    __shared__ float red[4];
    __shared__ float xs[256];
    if ((threadIdx.x & 63) == 0) red[threadIdx.x >> 6] = ss;
    __syncthreads();
    float tot = red[0] + red[1] + red[2] + red[3];
    float xn = x * rsqrtf(tot * (1.0f / 256.0f) + 1e-6f) * w[d];
    xs[d] = xn;
    __syncthreads();
    float out = xn;
    if (rope) {
        float rot = (d < 128) ? -xs[d + 128] : xs[d - 128];
        out = xn * cosb[s * 256 + d] + rot * sinb[s * 256 + d];
    }
    op[d] = out;
}

// ---------------- Kernel C: QK^T logits ----------------
// grid (64 l-tiles of 128, 4 kv). logits [KV][64][L]
__global__ __launch_bounds__(256) void k_qk(
    const float* __restrict__ q,        // [H][S][D] => per-kv contiguous [64][256]
    const float* __restrict__ cache_k,  // [KV][L][D]
    const float* __restrict__ kn,       // [KV][S][D]
    float* __restrict__ logits)
{
    const int l0 = blockIdx.x * 128;
    const int kh = blockIdx.y;
    const int tid = threadIdx.x;
    const int r0 = (tid >> 5) << 3;     // 8 q-rows per thread
    const int c0 = (tid & 31) << 2;     // 4 keys per thread
    __shared__ float qs[32][68];
    __shared__ float ks[32][132];
    const float* qbase = q + (size_t)kh * NQ_ * 256;
    float acc[8][4] = {};
    for (int d0 = 0; d0 < 256; d0 += 32) {
        #pragma unroll
        for (int i = 0; i < 8; i++) {
            int idx = i * 256 + tid;
            int e = idx & 31, n = idx >> 5;
            qs[e][n] = qbase[n * 256 + d0 + e];
        }
        #pragma unroll
        for (int i = 0; i < 16; i++) {
            int idx = i * 256 + tid;
            int e = idx & 31, c = idx >> 5;
            int l = l0 + c;
            const float* src = (l < LKEEP_)
                ? (cache_k + ((size_t)kh * L_ + l + S_) * 256)
                : (kn + ((size_t)kh * S_ + (l - LKEEP_)) * 256);
            ks[e][c] = src[d0 + e];
        }
        __syncthreads();
        #pragma unroll 8
        for (int e = 0; e < 32; e++) {
            float4 qa = *(const float4*)&qs[e][r0];
            float4 qb = *(const float4*)&qs[e][r0 + 4];
            float4 k4 = *(const float4*)&ks[e][c0];
            float qv[8] = {qa.x, qa.y, qa.z, qa.w, qb.x, qb.y, qb.z, qb.w};
            #pragma unroll
            for (int i = 0; i < 8; i++) {
                acc[i][0] = fmaf(qv[i], k4.x, acc[i][0]);
                acc[i][1] = fmaf(qv[i], k4.y, acc[i][1]);
                acc[i][2] = fmaf(qv[i], k4.z, acc[i][2]);
                acc[i][3] = fmaf(qv[i], k4.w, acc[i][3]);
            }
        }
        __syncthreads();
    }
    float* lp = logits + (size_t)kh * NQ_ * L_ + l0;
    #pragma unroll
    for (int i = 0; i < 8; i++) {
        *(float4*)&lp[(size_t)(r0 + i) * L_ + c0] =
            make_float4(acc[i][0], acc[i][1], acc[i][2], acc[i][3]);
    }
}

// ---------------- Kernel D: softmax (writes unnormalized exp + rowsum) ----------------
__global__ __launch_bounds__(256) void k_softmax(
    float* __restrict__ logits, const float* __restrict__ mask,
    float* __restrict__ rowsum)
{
    const int r = blockIdx.x;           // kh*64 + n
    const int s = r & 31;
    const int tid = threadIdx.x;
    float* lp = logits + (size_t)r * L_;
    const float* mp = mask + (size_t)s * L_;
    float m = -1e30f;
    for (int i = tid; i < L_; i += 256) m = fmaxf(m, lp[i] + mp[i]);
    #pragma unroll
    for (int w = 32; w; w >>= 1) m = fmaxf(m, __shfl_xor(m, w, 64));
    __shared__ float red[4];
    if ((tid & 63) == 0) red[tid >> 6] = m;
    __syncthreads();
    m = fmaxf(fmaxf(red[0], red[1]), fmaxf(red[2], red[3]));
    __syncthreads();
    float sum = 0.f;
    for (int i = tid; i < L_; i += 256) {
        float e = __expf(lp[i] + mp[i] - m);
        lp[i] = e;
        sum += e;
    }
    #pragma unroll
    for (int w = 32; w; w >>= 1) sum += __shfl_xor(sum, w, 64);
    if ((tid & 63) == 0) red[tid >> 6] = sum;
    __syncthreads();
    if (tid == 0) rowsum[r] = red[0] + red[1] + red[2] + red[3];
}

// ---------------- Kernel E: PV split-L partial GEMM ----------------
// grid (64 chunks of 128, 4 kv). pvpart [KV][64][64][256]
__global__ __launch_bounds__(256) void k_pv(
    const float* __restrict__ logits,
    const float* __restrict__ cache_v, const float* __restrict__ vn,
    float* __restrict__ pvpart)
{
    const int ch = blockIdx.x;
    const int kh = blockIdx.y;
    const int l0 = ch * 128;
    const int tid = threadIdx.x;
    const int r0 = (tid >> 5) << 3;     // 8 q-rows
    const int c0 = (tid & 31) << 3;     // 8 d-cols
    __shared__ float ps[128][68];
    __shared__ float vs[16][256];
    #pragma unroll
    for (int i = 0; i < 32; i++) {
        int idx = i * 256 + tid;
        int l = idx & 127, n = idx >> 7;
        ps[l][n] = logits[((size_t)kh * NQ_ + n) * L_ + l0 + l];
    }
    float acc[8][8] = {};
    for (int lc = 0; lc < 128; lc += 16) {
        #pragma unroll
        for (int i = 0; i < 16; i++) {
            int l = l0 + lc + i;
            const float* src = (l < LKEEP_)
                ? (cache_v + ((size_t)kh * L_ + l + S_) * 256)
                : (vn + ((size_t)kh * S_ + (l - LKEEP_)) * 256);
            vs[i][tid] = src[tid];
        }
        __syncthreads();
        #pragma unroll 4
        for (int l = 0; l < 16; l++) {
            float4 pa = *(const float4*)&ps[lc + l][r0];
            float4 pb = *(const float4*)&ps[lc + l][r0 + 4];
            float4 va = *(const float4*)&vs[l][c0];
            float4 vb = *(const float4*)&vs[l][c0 + 4];
            float pv[8] = {pa.x, pa.y, pa.z, pa.w, pb.x, pb.y, pb.z, pb.w};
            float vv[8] = {va.x, va.y, va.z, va.w, vb.x, vb.y, vb.z, vb.w};
            #pragma unroll
            for (int i = 0; i < 8; i++)
                #pragma unroll
                for (int j = 0; j < 8; j++)
                    acc[i][j] = fmaf(pv[i], vv[j], acc[i][j]);
        }
        __syncthreads();
    }
    float* op = pvpart + ((size_t)kh * 64 + ch) * NQ_ * 256;
    #pragma unroll
    for (int i = 0; i < 8; i++) {
        *(float4*)&op[(r0 + i) * 256 + c0] =
            make_float4(acc[i][0], acc[i][1], acc[i][2], acc[i][3]);
        *(float4*)&op[(r0 + i) * 256 + c0 + 4] =
            make_float4(acc[i][4], acc[i][5], acc[i][6], acc[i][7]);
    }
}

// ---------------- Kernel F: reduce PV partials + normalize + layout [S][H*D] ----------------
__global__ __launch_bounds__(256) void k_pvreduce(
    const float* __restrict__ pvpart, const float* __restrict__ rowsum,
    float* __restrict__ attn_out)
{
    const int b = blockIdx.x;           // 0..255 = kh*64+n
    const int kh = b >> 6, n = b & 63;
    const int d = threadIdx.x;
    float sum = 0.f;
    const float* pp = pvpart + ((size_t)kh * 64 * NQ_ + n) * 256 + d;
    for (int c = 0; c < 64; c++) sum += pp[(size_t)c * NQ_ * 256];
    const float inv = 1.0f / rowsum[b];
    const int h = kh * 2 + (n >> 5), s = n & 31;
    attn_out[(size_t)s * 2048 + h * 256 + d] = sum * inv;
}

// ---------------- Kernel G: generic 32-row GEMM with K-split (used for W_o) ----------------
__global__ __launch_bounds__(256) void k_gemm32(
    const float* __restrict__ in, int ldin,
    const float* __restrict__ W, int ldw,
    float* __restrict__ outp, int kslen)
{
    const int col0 = blockIdx.x * 64;
    const int kp   = blockIdx.y;
    const int kbase = kp * kslen;
    const int tc = (threadIdx.x & 31) * 2;
    const int tr = threadIdx.x >> 5;
    __shared__ float hs[32][68];
    float acc[4][2] = {};
    for (int e0 = 0; e0 < kslen; e0 += 64) {
        #pragma unroll
        for (int i = 0; i < 8; i++) {
            int idx = i * 256 + threadIdx.x;
            hs[idx >> 6][idx & 63] = in[(idx >> 6) * ldin + kbase + e0 + (idx & 63)];
        }
        __syncthreads();
        #pragma unroll 4
        for (int e = 0; e < 64; e += 4) {
            float4 h0 = *(const float4*)&hs[tr][e];
            float4 h1 = *(const float4*)&hs[tr + 8][e];
            float4 h2 = *(const float4*)&hs[tr + 16][e];
            float4 h3 = *(const float4*)&hs[tr + 24][e];
            #pragma unroll
            for (int j = 0; j < 4; j++) {
                float2 w = *(const float2*)&W[(size_t)(kbase + e0 + e + j) * ldw + col0 + tc];
                float a0 = ((const float*)&h0)[j];
                float a1 = ((const float*)&h1)[j];
                float a2 = ((const float*)&h2)[j];
                float a3 = ((const float*)&h3)[j];
                acc[0][0] = fmaf(a0, w.x, acc[0][0]); acc[0][1] = fmaf(a0, w.y, acc[0][1]);
                acc[1][0] = fmaf(a1, w.x, acc[1][0]); acc[1][1] = fmaf(a1, w.y, acc[1][1]);
                acc[2][0] = fmaf(a2, w.x, acc[2][0]); acc[2][1] = fmaf(a2, w.y, acc[2][1]);
                acc[3][0] = fmaf(a3, w.x, acc[3][0]); acc[3][1] = fmaf(a3, w.y, acc[3][1]);
            }
        }
        __syncthreads();
    }
    float* op = outp + (size_t)kp * 32 * ldw;
    #pragma unroll
    for (int i = 0; i < 4; i++) {
        int r = tr + i * 8;
        *(float2*)&op[r * ldw + col0 + tc] = make_float2(acc[i][0], acc[i][1]);
    }
}

// ---------------- Kernel H: sum 4 W_o partials into d_out ----------------
__global__ __launch_bounds__(256) void k_gsum(const float* __restrict__ gpart,
                                              float* __restrict__ out)
{
    int idx = blockIdx.x * 256 + threadIdx.x;   // grid 320 -> 81920 exact
    out[idx] = gpart[idx] + gpart[81920 + idx] + gpart[163840 + idx] + gpart[245760 + idx];
}

// ---------------- host ----------------
extern "C" void kernel_launch(void* const* d_in, const int* in_sizes, int n_in,
                              void* d_out, int out_size, void* d_ws, size_t ws_size,
                              hipStream_t stream)
{
    const float* hidden  = (const float*)d_in[0];
    const float* cosb    = (const float*)d_in[1];
    const float* sinb    = (const float*)d_in[2];
    const float* cache_k = (const float*)d_in[3];
    const float* cache_v = (const float*)d_in[4];
    const float* mask    = (const float*)d_in[5];
    const float* Wq      = (const float*)d_in[6];
    const float* Wk      = (const float*)d_in[7];
    const float* Wv      = (const float*)d_in[8];
    const float* Wo      = (const float*)d_in[9];
    const float* qw      = (const float*)d_in[10];
    const float* kw      = (const float*)d_in[11];
    const float* vw      = (const float*)d_in[12];

    float* ws = (float*)d_ws;
    size_t off = 0;
    float* qkv_part = ws + off; off += (size_t)4 * 32 * 4096;   // 524288
    float* qb       = ws + off; off += (size_t)H_ * S_ * D_;    // 65536
    float* knb      = ws + off; off += (size_t)KV_ * S_ * D_;   // 32768
    float* vnb      = ws + off; off += (size_t)KV_ * S_ * D_;   // 32768
    float* logits   = ws + off; off += (size_t)KV_ * NQ_ * L_;  // 2097152
    float* rowsum   = ws + off; off += 256;
    float* attn_out = ws + off; off += (size_t)S_ * H_ * D_;    // 65536
    float* gpart    = ws + off; off += (size_t)4 * 32 * 2560;   // 327680
    float* pvpart   = ws + off; off += (size_t)KV_ * 64 * NQ_ * 256; // 4194304

    k_qkv_proj<<<dim3(64, 4), 256, 0, stream>>>(hidden, Wq, Wk, Wv, qkv_part);
    k_rms_rope<<<512, 256, 0, stream>>>(qkv_part, cosb, sinb, qw, kw, vw, qb, knb, vnb);
    k_qk<<<dim3(64, 4), 256, 0, stream>>>(qb, cache_k, knb, logits);
    k_softmax<<<256, 256, 0, stream>>>(logits, mask, rowsum);
    k_pv<<<dim3(64, 4), 256, 0, stream>>>(logits, cache_v, vnb, pvpart);
    k_pvreduce<<<256, 256, 0, stream>>>(pvpart, rowsum, attn_out);
    k_gemm32<<<dim3(40, 4), 256, 0, stream>>>(attn_out, 2048, Wo, 2560, gpart, 512);
    k_gsum<<<320, 256, 0, stream>>>(gpart, (float*)d_out);
}